// Round 5
// baseline (223.134 us; speedup 1.0000x reference)
//
#include <hip/hip_runtime.h>

#define IN_FEAT 64
#define OUT_FEAT 64
#define CAP 64   // padded-CSR capacity; deg ~ Poisson(16), P(>64) ~ e^-42
#define NSHARD 8
#define BLKS_PER_SHARD 256
#define XSTR 136 // fused x-tile row stride (f16): 272B -> conflict-free frag reads

typedef __attribute__((ext_vector_type(8))) _Float16 half8;
typedef __attribute__((ext_vector_type(4))) float floatx4;
typedef __attribute__((ext_vector_type(4))) int intx4;

// ---- K0: h (f32) -> h16 (f16), 8 elems/thread; deg-zeroing folded in ----
// (conv precedes fill on-stream, so deg is zero before any atomic).
__global__ __launch_bounds__(256) void conv_kernel(const float* __restrict__ h,
        _Float16* __restrict__ h16, int total8, int* __restrict__ deg, int N) {
    int t = blockIdx.x * 256 + threadIdx.x;
    int n4 = N >> 2;
    if (t < n4) ((intx4*)deg)[t] = (intx4){0, 0, 0, 0};
    else if (t - n4 < (N & 3)) deg[(n4 << 2) + (t - n4)] = 0;
    if (t >= total8) return;
    const float4* p = (const float4*)(h + (long long)t * 8);
    float4 a = p[0], c = p[1];
    half8 v;
    v[0] = (_Float16)a.x; v[1] = (_Float16)a.y;
    v[2] = (_Float16)a.z; v[3] = (_Float16)a.w;
    v[4] = (_Float16)c.x; v[5] = (_Float16)c.y;
    v[6] = (_Float16)c.z; v[7] = (_Float16)c.w;
    *(half8*)(h16 + (long long)t * 8) = v;
}

// ---- K1: XCD-sharded padded-CSR fill (R1 structure, proven ~73us). ----
// Pinned across occupancy 22-80% and MLP 1-28: scattered-transaction wall.
// nt on the dst stream (zero reuse) keeps csr lines in L2: R3 measured
// WRITE_SIZE 83->65MB from this hint alone.
__global__ __launch_bounds__(256) void fill_kernel(const int* __restrict__ src,
        const int* __restrict__ dst, int* __restrict__ deg,
        int* __restrict__ csr, int E, int shard_sz) {
    int shard = blockIdx.x & (NSHARD - 1);
    int blk   = blockIdx.x >> 3;            // 0..BLKS_PER_SHARD-1
    int lo = shard * shard_sz;
    int hi = lo + shard_sz;
    int stride = BLKS_PER_SHARD * 256;
    int E4 = E >> 2;
    const intx4* dst4 = (const intx4*)dst;
    for (int e4 = blk * 256 + threadIdx.x; e4 < E4; e4 += stride) {
        intx4 d = __builtin_nontemporal_load(&dst4[e4]);
        int e = e4 << 2;
        if (d.x >= lo && d.x < hi) {
            int s = src[e];
            int pos = atomicAdd(&deg[d.x], 1);
            if (pos < CAP) csr[(d.x << 6) | pos] = s;
        }
        if (d.y >= lo && d.y < hi) {
            int s = src[e + 1];
            int pos = atomicAdd(&deg[d.y], 1);
            if (pos < CAP) csr[(d.y << 6) | pos] = s;
        }
        if (d.z >= lo && d.z < hi) {
            int s = src[e + 2];
            int pos = atomicAdd(&deg[d.z], 1);
            if (pos < CAP) csr[(d.z << 6) | pos] = s;
        }
        if (d.w >= lo && d.w < hi) {
            int s = src[e + 3];
            int pos = atomicAdd(&deg[d.w], 1);
            if (pos < CAP) csr[(d.w << 6) | pos] = s;
        }
    }
    if (blk == 0) {
        for (int e = (E4 << 2) + threadIdx.x; e < E; e += 256) {
            int dd = dst[e];
            if (dd >= lo && dd < hi) {
                int s = src[e];
                int pos = atomicAdd(&deg[dd], 1);
                if (pos < CAP) csr[(dd << 6) | pos] = s;
            }
        }
    }
}

// ---- K2+K3 fused: gather-mean -> LDS x-tile -> MFMA linear. ----
// Block owns 16 nodes (one MFMA M-tile). 4 waves gather 4 nodes each
// (2-pair interleave, 16 outstanding rows/wave); x never round-trips
// global (saves 51MB). After barrier, wave w computes out cols 16w..+15.
// Requires h16 in ws (out is being overwritten while other blocks gather).
__global__ __launch_bounds__(256) void gather_linear_kernel(
        const _Float16* __restrict__ h16, const int* __restrict__ deg,
        const int* __restrict__ csr, const float* __restrict__ W,
        const float* __restrict__ b, float* __restrict__ out, int N) {
    __shared__ _Float16 wlds[16 * 64 * 8];             // 16KB W fragments
    __shared__ __attribute__((aligned(16))) _Float16 xt[16 * XSTR];
    int wave = threadIdx.x >> 6;
    int lane = threadIdx.x & 63;
    int quad = lane >> 4;
    int l16  = lane & 15;

    // cooperative W stage (coalesced f32), same fragment layout as before.
    for (int i = threadIdx.x; i < 64 * 2 * IN_FEAT; i += 256) {
        int row = i >> 7, col = i & 127;
        int t = row >> 4, lr = row & 15;
        int q = col >> 5, qd = (col & 31) >> 3, j = col & 7;
        wlds[(((t * 4 + q) * 64) + (qd * 16 + lr)) * 8 + j] = (_Float16)W[i];
    }

    int node_base = blockIdx.x * 16;
    int n0 = node_base + wave * 4;
#pragma unroll
    for (int it = 0; it < 2; ++it) {
        int a = n0 + it * 2;
        if (a >= N) continue;          // guarded (no return before barrier)
        int bn = a + 1;
        bool hasB = bn < N;
        int cntA = deg[a];
        int cntB = hasB ? deg[bn] : 0;
        int rawA = csr[(a << 6) | lane];                 // coalesced 256B
        int rawB = hasB ? csr[(bn << 6) | lane] : 0;
        _Float16 selfA = h16[(long long)a * IN_FEAT + lane];
        _Float16 selfB = hasB ? h16[(long long)bn * IN_FEAT + lane] : (_Float16)0.0f;
        int mA = cntA < CAP ? cntA : CAP;
        int mB = cntB < CAP ? cntB : CAP;
        int sidA = (lane < mA) ? rawA : 0;
        int sidB = (lane < mB) ? rawB : 0;
        float accA0 = 0.f, accA1 = 0.f, accB0 = 0.f, accB1 = 0.f;
        int mmax = mA > mB ? mA : mB;
        for (int j = 0; j < mmax; j += 8) {
            float va[8], vb[8];
#pragma unroll
            for (int k = 0; k < 8; ++k) {
                int sA = __shfl(sidA, j + k);
                int sB = __shfl(sidB, j + k);
                va[k] = (float)h16[(long long)sA * IN_FEAT + lane];
                vb[k] = (float)h16[(long long)sB * IN_FEAT + lane];
            }
#pragma unroll
            for (int k = 0; k < 8; ++k) {
                float xa = (j + k < mA) ? va[k] : 0.0f;
                float xb = (j + k < mB) ? vb[k] : 0.0f;
                if (k & 1) { accA1 += xa; accB1 += xb; }
                else       { accA0 += xa; accB0 += xb; }
            }
        }
        int rA = wave * 4 + it * 2;
        xt[rA * XSTR + lane] = selfA;
        xt[rA * XSTR + IN_FEAT + lane] =
            (_Float16)((accA0 + accA1) / fmaxf((float)cntA, 1.0f));
        if (hasB) {
            xt[(rA + 1) * XSTR + lane] = selfB;
            xt[(rA + 1) * XSTR + IN_FEAT + lane] =
                (_Float16)((accB0 + accB1) / fmaxf((float)cntB, 1.0f));
        }
    }
    __syncthreads();

    // linear: wave w = output tile t. af identical across waves (LDS reads).
    half8 bf[4];
#pragma unroll
    for (int q = 0; q < 4; ++q)
        bf[q] = *(const half8*)&wlds[((wave * 4 + q) * 64 + lane) * 8];
    float bias = b[16 * wave + l16];
    floatx4 acc = {0.0f, 0.0f, 0.0f, 0.0f};
#pragma unroll
    for (int q = 0; q < 4; ++q) {
        half8 af = *(const half8*)&xt[l16 * XSTR + 32 * q + 8 * quad];
        acc = __builtin_amdgcn_mfma_f32_16x16x32_f16(af, bf[q], acc, 0, 0, 0);
    }
#pragma unroll
    for (int r = 0; r < 4; ++r) {
        int n = node_base + quad * 4 + r;
        if (n < N)
            out[(long long)n * OUT_FEAT + 16 * wave + l16] = acc[r] + bias;
    }
}

// ---- Fallback K2: gather-mean, 2-node interleaved chains (R4, proven). ----
__global__ __launch_bounds__(256) void gather_kernel(const _Float16* __restrict__ h16,
        const int* __restrict__ deg, int* csr_x, int N) {
    int wave = threadIdx.x >> 6;
    int lane = threadIdx.x & 63;
    int n0 = (blockIdx.x * 4 + wave) * 4;
    if (n0 >= N) return;
#pragma unroll
    for (int it = 0; it < 2; ++it) {
        int a = n0 + it * 2;
        if (a >= N) return;
        int bn = a + 1;
        bool hasB = bn < N;
        int cntA = deg[a];
        int cntB = hasB ? deg[bn] : 0;
        int rawA = csr_x[(a << 6) | lane];
        int rawB = hasB ? csr_x[(bn << 6) | lane] : 0;
        _Float16 selfA = h16[(long long)a * IN_FEAT + lane];
        _Float16 selfB = hasB ? h16[(long long)bn * IN_FEAT + lane] : (_Float16)0.0f;
        int mA = cntA < CAP ? cntA : CAP;
        int mB = cntB < CAP ? cntB : CAP;
        int sidA = (lane < mA) ? rawA : 0;
        int sidB = (lane < mB) ? rawB : 0;
        float accA0 = 0.f, accA1 = 0.f, accB0 = 0.f, accB1 = 0.f;
        int mmax = mA > mB ? mA : mB;
        for (int j = 0; j < mmax; j += 8) {
            float va[8], vb[8];
#pragma unroll
            for (int k = 0; k < 8; ++k) {
                int sA = __shfl(sidA, j + k);
                int sB = __shfl(sidB, j + k);
                va[k] = (float)h16[(long long)sA * IN_FEAT + lane];
                vb[k] = (float)h16[(long long)sB * IN_FEAT + lane];
            }
#pragma unroll
            for (int k = 0; k < 8; ++k) {
                float xa = (j + k < mA) ? va[k] : 0.0f;
                float xb = (j + k < mB) ? vb[k] : 0.0f;
                if (k & 1) { accA1 += xa; accB1 += xb; }
                else       { accA0 += xa; accB0 += xb; }
            }
        }
        float meanA = (accA0 + accA1) / fmaxf((float)cntA, 1.0f);
        _Float16* xrA = (_Float16*)(csr_x + ((long long)a << 6));
        xrA[lane] = selfA;
        xrA[IN_FEAT + lane] = (_Float16)meanA;
        if (hasB) {
            float meanB = (accB0 + accB1) / fmaxf((float)cntB, 1.0f);
            _Float16* xrB = (_Float16*)(csr_x + ((long long)bn << 6));
            xrB[lane] = selfB;
            xrB[IN_FEAT + lane] = (_Float16)meanB;
        }
    }
}

// ---- Fallback K3: MFMA linear, LDS-staged W (R4, proven). ----
__global__ __launch_bounds__(256) void linear_kernel(const int* __restrict__ x_i,
        const float* __restrict__ W, const float* __restrict__ b,
        float* __restrict__ out, int N) {
    const _Float16* x = (const _Float16*)x_i;
    __shared__ _Float16 wlds[16 * 64 * 8];   // 16KB: [f=t*4+q][lane][j]
    int wave = threadIdx.x >> 6;
    int lane = threadIdx.x & 63;
    int quad = lane >> 4;
    int l16  = lane & 15;

    for (int i = threadIdx.x; i < 64 * 2 * IN_FEAT; i += 256) {
        int row = i >> 7, col = i & 127;
        int t = row >> 4, lr = row & 15;
        int q = col >> 5, qd = (col & 31) >> 3, j = col & 7;
        wlds[(((t * 4 + q) * 64) + (qd * 16 + lr)) * 8 + j] = (_Float16)W[i];
    }
    __syncthreads();

    int node_base = (blockIdx.x * 4 + wave) * 16;
    if (node_base >= N) return;

    half8 bf[4][4];
#pragma unroll
    for (int t = 0; t < 4; ++t)
#pragma unroll
        for (int q = 0; q < 4; ++q)
            bf[t][q] = *(const half8*)&wlds[((t * 4 + q) * 64 + lane) * 8];
    float bias[4];
#pragma unroll
    for (int t = 0; t < 4; ++t) bias[t] = b[16 * t + l16];

    int mrow = node_base + l16;
    if (mrow >= N) mrow = N - 1;

    floatx4 z = {0.0f, 0.0f, 0.0f, 0.0f};
    floatx4 acc[4] = {z, z, z, z};
#pragma unroll
    for (int q = 0; q < 4; ++q) {
        half8 af = *(const half8*)&x[(long long)mrow * (2 * IN_FEAT) + 32 * q + 8 * quad];
#pragma unroll
        for (int t = 0; t < 4; ++t)
            acc[t] = __builtin_amdgcn_mfma_f32_16x16x32_f16(af, bf[t][q], acc[t], 0, 0, 0);
    }
#pragma unroll
    for (int t = 0; t < 4; ++t)
#pragma unroll
        for (int r = 0; r < 4; ++r) {
            int n = node_base + quad * 4 + r;
            if (n < N)
                out[(long long)n * OUT_FEAT + 16 * t + l16] = acc[t][r] + bias[t];
        }
}

extern "C" void kernel_launch(void* const* d_in, const int* in_sizes, int n_in,
                              void* d_out, int out_size, void* d_ws, size_t ws_size,
                              hipStream_t stream) {
    const float* h   = (const float*)d_in[0];
    const int*   src = (const int*)d_in[1];
    const int*   dst = (const int*)d_in[2];
    const float* W   = (const float*)d_in[3];
    const float* b   = (const float*)d_in[4];
    float* out = (float*)d_out;

    int N = in_sizes[0] / IN_FEAT;   // 100000
    int E = in_sizes[1];             // 1600000

    // ws: deg[N] | csr[N*64] | (fused path) h16[N*64 f16]
    int* deg = (int*)d_ws;
    int* csr = deg + N;
    size_t base = (((size_t)N * 65 * sizeof(int)) + 15) & ~(size_t)15;
    bool fused = ws_size >= base + (size_t)N * IN_FEAT * sizeof(_Float16);
    // fallback: h16 in front of d_out (dead until linear rewrites out;
    // fallback linear reads x from ws only -> no race).
    _Float16* h16 = fused ? (_Float16*)((char*)d_ws + base) : (_Float16*)out;

    int total8 = N * IN_FEAT / 8;
    conv_kernel<<<(total8 + 255) / 256, 256, 0, stream>>>(h, h16, total8, deg, N);

    int shard_sz = (N + NSHARD - 1) / NSHARD;   // 12500
    fill_kernel<<<NSHARD * BLKS_PER_SHARD, 256, 0, stream>>>(src, dst, deg, csr, E, shard_sz);

    if (fused) {
        gather_linear_kernel<<<(N + 15) / 16, 256, 0, stream>>>(h16, deg, csr, W, b, out, N);
    } else {
        gather_kernel<<<(N + 15) / 16, 256, 0, stream>>>(h16, deg, csr, N);
        int tiles = (N + 15) / 16;
        linear_kernel<<<(tiles + 3) / 4, 256, 0, stream>>>(csr, W, b, out, N);
    }
}

// Round 6
// 213.118 us; speedup vs baseline: 1.0470x; 1.0470x over previous
//
#include <hip/hip_runtime.h>

#define IN_FEAT 64
#define OUT_FEAT 64
#define CAP 48   // fill capacity; deg~Poisson(16), P(>48)<=3e-10/node.
                 // Row STRIDE stays 64 ints (256B): fill touches only the
                 // first 3 of 4 cache lines/row -> 2.4MB L2 window/shard
                 // (was 3.2MB, thrashed); x[128 f16] still fits the row.
#define NSHARD 8
#define BLKS_PER_SHARD 256

typedef __attribute__((ext_vector_type(8))) _Float16 half8;
typedef __attribute__((ext_vector_type(4))) float floatx4;
typedef __attribute__((ext_vector_type(4))) int intx4;

// ---- K0: h (f32) -> h16 (f16), 8 elems/thread; deg-zeroing folded in ----
__global__ __launch_bounds__(256) void conv_kernel(const float* __restrict__ h,
        _Float16* __restrict__ h16, int total8, int* __restrict__ deg, int N) {
    int t = blockIdx.x * 256 + threadIdx.x;
    int n4 = N >> 2;
    if (t < n4) ((intx4*)deg)[t] = (intx4){0, 0, 0, 0};
    else if (t - n4 < (N & 3)) deg[(n4 << 2) + (t - n4)] = 0;
    if (t >= total8) return;
    const float4* p = (const float4*)(h + (long long)t * 8);
    float4 a = p[0], c = p[1];
    half8 v;
    v[0] = (_Float16)a.x; v[1] = (_Float16)a.y;
    v[2] = (_Float16)a.z; v[3] = (_Float16)a.w;
    v[4] = (_Float16)c.x; v[5] = (_Float16)c.y;
    v[6] = (_Float16)c.z; v[7] = (_Float16)c.w;
    *(half8*)(h16 + (long long)t * 8) = v;
}

// ---- K1: XCD-sharded padded-CSR fill (R1 structure). ----
// WRITE_SIZE ~80MB vs csr 25.6MB => csr lines written back ~3x: the 3.2MB
// shard window + streams overflowed the 4MB XCD L2. CAP=48 (stride 64)
// shrinks the touched footprint to 2.4MB; nt dst loads keep the stream
// from evicting it. deg counts ALL edges (true mean divisor).
__global__ __launch_bounds__(256) void fill_kernel(const int* __restrict__ src,
        const int* __restrict__ dst, int* __restrict__ deg,
        int* __restrict__ csr, int E, int shard_sz) {
    int shard = blockIdx.x & (NSHARD - 1);
    int blk   = blockIdx.x >> 3;            // 0..BLKS_PER_SHARD-1
    int lo = shard * shard_sz;
    int hi = lo + shard_sz;
    int stride = BLKS_PER_SHARD * 256;
    int E4 = E >> 2;
    const intx4* dst4 = (const intx4*)dst;
    for (int e4 = blk * 256 + threadIdx.x; e4 < E4; e4 += stride) {
        intx4 d = __builtin_nontemporal_load(&dst4[e4]);
        int e = e4 << 2;
        if (d.x >= lo && d.x < hi) {
            int s = src[e];
            int pos = atomicAdd(&deg[d.x], 1);
            if (pos < CAP) csr[(d.x << 6) | pos] = s;
        }
        if (d.y >= lo && d.y < hi) {
            int s = src[e + 1];
            int pos = atomicAdd(&deg[d.y], 1);
            if (pos < CAP) csr[(d.y << 6) | pos] = s;
        }
        if (d.z >= lo && d.z < hi) {
            int s = src[e + 2];
            int pos = atomicAdd(&deg[d.z], 1);
            if (pos < CAP) csr[(d.z << 6) | pos] = s;
        }
        if (d.w >= lo && d.w < hi) {
            int s = src[e + 3];
            int pos = atomicAdd(&deg[d.w], 1);
            if (pos < CAP) csr[(d.w << 6) | pos] = s;
        }
    }
    if (blk == 0) {
        for (int e = (E4 << 2) + threadIdx.x; e < E; e += 256) {
            int dd = dst[e];
            if (dd >= lo && dd < hi) {
                int s = src[e];
                int pos = atomicAdd(&deg[dd], 1);
                if (pos < CAP) csr[(dd << 6) | pos] = s;
            }
        }
    }
}

// ---- K2: gather-mean, 2-node interleaved chains (R4, proven). ----
// Writes x[n] = [h16[n] | mean f16] aliased over csr row n.
__global__ __launch_bounds__(256) void gather_kernel(const _Float16* __restrict__ h16,
        const int* __restrict__ deg, int* csr_x, int N) {
    int wave = threadIdx.x >> 6;
    int lane = threadIdx.x & 63;
    int n0 = (blockIdx.x * 4 + wave) * 4;
    if (n0 >= N) return;
#pragma unroll
    for (int it = 0; it < 2; ++it) {
        int a = n0 + it * 2;
        if (a >= N) return;
        int bn = a + 1;
        bool hasB = bn < N;
        int cntA = deg[a];
        int cntB = hasB ? deg[bn] : 0;
        int rawA = csr_x[(a << 6) | lane];                 // coalesced
        int rawB = hasB ? csr_x[(bn << 6) | lane] : 0;
        _Float16 selfA = h16[(long long)a * IN_FEAT + lane];
        _Float16 selfB = hasB ? h16[(long long)bn * IN_FEAT + lane] : (_Float16)0.0f;
        int mA = cntA < CAP ? cntA : CAP;
        int mB = cntB < CAP ? cntB : CAP;
        int sidA = (lane < mA) ? rawA : 0;
        int sidB = (lane < mB) ? rawB : 0;
        float accA0 = 0.f, accA1 = 0.f, accB0 = 0.f, accB1 = 0.f;
        int mmax = mA > mB ? mA : mB;
        for (int j = 0; j < mmax; j += 8) {
            float va[8], vb[8];
#pragma unroll
            for (int k = 0; k < 8; ++k) {
                int sA = __shfl(sidA, j + k);
                int sB = __shfl(sidB, j + k);
                va[k] = (float)h16[(long long)sA * IN_FEAT + lane];
                vb[k] = (float)h16[(long long)sB * IN_FEAT + lane];
            }
#pragma unroll
            for (int k = 0; k < 8; ++k) {
                float xa = (j + k < mA) ? va[k] : 0.0f;
                float xb = (j + k < mB) ? vb[k] : 0.0f;
                if (k & 1) { accA1 += xa; accB1 += xb; }
                else       { accA0 += xa; accB0 += xb; }
            }
        }
        float meanA = (accA0 + accA1) / fmaxf((float)cntA, 1.0f);
        _Float16* xrA = (_Float16*)(csr_x + ((long long)a << 6));
        xrA[lane] = selfA;
        xrA[IN_FEAT + lane] = (_Float16)meanA;
        if (hasB) {
            float meanB = (accB0 + accB1) / fmaxf((float)cntB, 1.0f);
            _Float16* xrB = (_Float16*)(csr_x + ((long long)bn << 6));
            xrB[lane] = selfB;
            xrB[IN_FEAT + lane] = (_Float16)meanB;
        }
    }
}

// ---- K3: MFMA linear, LDS-staged W (R4, proven). ----
__global__ __launch_bounds__(256) void linear_kernel(const int* __restrict__ x_i,
        const float* __restrict__ W, const float* __restrict__ b,
        float* __restrict__ out, int N) {
    const _Float16* x = (const _Float16*)x_i;
    __shared__ _Float16 wlds[16 * 64 * 8];   // 16KB: [f=t*4+q][lane][j]
    int wave = threadIdx.x >> 6;
    int lane = threadIdx.x & 63;
    int quad = lane >> 4;
    int l16  = lane & 15;

    for (int i = threadIdx.x; i < 64 * 2 * IN_FEAT; i += 256) {
        int row = i >> 7, col = i & 127;
        int t = row >> 4, lr = row & 15;
        int q = col >> 5, qd = (col & 31) >> 3, j = col & 7;
        wlds[(((t * 4 + q) * 64) + (qd * 16 + lr)) * 8 + j] = (_Float16)W[i];
    }
    __syncthreads();

    int node_base = (blockIdx.x * 4 + wave) * 16;
    if (node_base >= N) return;

    half8 bf[4][4];
#pragma unroll
    for (int t = 0; t < 4; ++t)
#pragma unroll
        for (int q = 0; q < 4; ++q)
            bf[t][q] = *(const half8*)&wlds[((t * 4 + q) * 64 + lane) * 8];
    float bias[4];
#pragma unroll
    for (int t = 0; t < 4; ++t) bias[t] = b[16 * t + l16];

    int mrow = node_base + l16;
    if (mrow >= N) mrow = N - 1;

    floatx4 z = {0.0f, 0.0f, 0.0f, 0.0f};
    floatx4 acc[4] = {z, z, z, z};
#pragma unroll
    for (int q = 0; q < 4; ++q) {
        half8 af = *(const half8*)&x[(long long)mrow * (2 * IN_FEAT) + 32 * q + 8 * quad];
#pragma unroll
        for (int t = 0; t < 4; ++t)
            acc[t] = __builtin_amdgcn_mfma_f32_16x16x32_f16(af, bf[t][q], acc[t], 0, 0, 0);
    }
#pragma unroll
    for (int t = 0; t < 4; ++t)
#pragma unroll
        for (int r = 0; r < 4; ++r) {
            int n = node_base + quad * 4 + r;
            if (n < N)
                out[(long long)n * OUT_FEAT + 16 * t + l16] = acc[t][r] + bias[t];
        }
}

extern "C" void kernel_launch(void* const* d_in, const int* in_sizes, int n_in,
                              void* d_out, int out_size, void* d_ws, size_t ws_size,
                              hipStream_t stream) {
    const float* h   = (const float*)d_in[0];
    const int*   src = (const int*)d_in[1];
    const int*   dst = (const int*)d_in[2];
    const float* W   = (const float*)d_in[3];
    const float* b   = (const float*)d_in[4];
    float* out = (float*)d_out;

    int N = in_sizes[0] / IN_FEAT;   // 100000
    int E = in_sizes[1];             // 1600000

    // ws (ints): deg[N] | csr[N*64] (x[N][128] f16 aliased over csr rows)
    int* deg = (int*)d_ws;
    int* csr = deg + N;
    // h16 lives in the front 12.8 MB of d_out (dead until linear_kernel
    // rewrites d_out; linear reads only from ws -> no race).
    _Float16* h16 = (_Float16*)out;

    int total8 = N * IN_FEAT / 8;
    conv_kernel<<<(total8 + 255) / 256, 256, 0, stream>>>(h, h16, total8, deg, N);

    int shard_sz = (N + NSHARD - 1) / NSHARD;   // 12500
    fill_kernel<<<NSHARD * BLKS_PER_SHARD, 256, 0, stream>>>(src, dst, deg, csr, E, shard_sz);

    int gather_blocks = (N + 15) / 16;       // 4 waves x 4 nodes (2 pairs)
    gather_kernel<<<gather_blocks, 256, 0, stream>>>(h16, deg, csr, N);

    int tiles = (N + 15) / 16;
    linear_kernel<<<(tiles + 3) / 4, 256, 0, stream>>>(csr, W, b, out, N);
}

// Round 7
// 210.850 us; speedup vs baseline: 1.0583x; 1.0108x over previous
//
#include <hip/hip_runtime.h>

#define IN_FEAT 64
#define OUT_FEAT 64
#define CAP 48   // fill capacity; deg~Poisson(16), P(>48)<=3e-10/node.
                 // Row stride stays 64 ints; fill touches 3 of 4 lines/row.
#define NSHARD 8
#define BLKS_PER_SHARD 256
#define DEGS 16  // deg stride (ints): one 64B line per node. Dense deg put
                 // ~256 atomic RMWs on each L2 line (16 nodes x deg 16);
                 // that same-line serialization matches the occupancy/MLP/
                 // CAP-invariant ~75us wall. Line-exclusive deg leaves only
                 // the inherent 16 same-address atomics per node.

typedef __attribute__((ext_vector_type(8))) _Float16 half8;
typedef __attribute__((ext_vector_type(4))) float floatx4;
typedef __attribute__((ext_vector_type(4))) int intx4;

// ---- K0: h (f32) -> h16 (f16), 8 elems/thread; deg-zeroing folded in ----
__global__ __launch_bounds__(256) void conv_kernel(const float* __restrict__ h,
        _Float16* __restrict__ h16, int total8, int* __restrict__ deg, int N) {
    int t = blockIdx.x * 256 + threadIdx.x;
    int z4 = (N * DEGS) >> 2;
    if (t < z4) ((intx4*)deg)[t] = (intx4){0, 0, 0, 0};
    if (t >= total8) return;
    const float4* p = (const float4*)(h + (long long)t * 8);
    float4 a = p[0], c = p[1];
    half8 v;
    v[0] = (_Float16)a.x; v[1] = (_Float16)a.y;
    v[2] = (_Float16)a.z; v[3] = (_Float16)a.w;
    v[4] = (_Float16)c.x; v[5] = (_Float16)c.y;
    v[6] = (_Float16)c.z; v[7] = (_Float16)c.w;
    *(half8*)(h16 + (long long)t * 8) = v;
}

// ---- K1: XCD-sharded padded-CSR fill (R1 structure + line-padded deg). ----
// shard = blockIdx % 8 = XCD id under round-robin dispatch; per-shard
// deg+csr window (800KB + 2.4MB) L2-resident. No nt (cost 3.5us, R1 vs R5).
__global__ __launch_bounds__(256) void fill_kernel(const int* __restrict__ src,
        const int* __restrict__ dst, int* __restrict__ deg,
        int* __restrict__ csr, int E, int shard_sz) {
    int shard = blockIdx.x & (NSHARD - 1);
    int blk   = blockIdx.x >> 3;            // 0..BLKS_PER_SHARD-1
    int lo = shard * shard_sz;
    int hi = lo + shard_sz;
    int stride = BLKS_PER_SHARD * 256;
    int E4 = E >> 2;
    const int4* dst4 = (const int4*)dst;
    for (int e4 = blk * 256 + threadIdx.x; e4 < E4; e4 += stride) {
        int4 d = dst4[e4];
        int e = e4 << 2;
        if (d.x >= lo && d.x < hi) {
            int s = src[e];
            int pos = atomicAdd(&deg[d.x << 4], 1);
            if (pos < CAP) csr[(d.x << 6) | pos] = s;
        }
        if (d.y >= lo && d.y < hi) {
            int s = src[e + 1];
            int pos = atomicAdd(&deg[d.y << 4], 1);
            if (pos < CAP) csr[(d.y << 6) | pos] = s;
        }
        if (d.z >= lo && d.z < hi) {
            int s = src[e + 2];
            int pos = atomicAdd(&deg[d.z << 4], 1);
            if (pos < CAP) csr[(d.z << 6) | pos] = s;
        }
        if (d.w >= lo && d.w < hi) {
            int s = src[e + 3];
            int pos = atomicAdd(&deg[d.w << 4], 1);
            if (pos < CAP) csr[(d.w << 6) | pos] = s;
        }
    }
    if (blk == 0) {
        for (int e = (E4 << 2) + threadIdx.x; e < E; e += 256) {
            int dd = dst[e];
            if (dd >= lo && dd < hi) {
                int s = src[e];
                int pos = atomicAdd(&deg[dd << 4], 1);
                if (pos < CAP) csr[(dd << 6) | pos] = s;
            }
        }
    }
}

// ---- K2: gather-mean, 2-node interleaved chains (R4, proven). ----
// Writes x[n] = [h16[n] | mean f16] aliased over csr row n.
__global__ __launch_bounds__(256) void gather_kernel(const _Float16* __restrict__ h16,
        const int* __restrict__ deg, int* csr_x, int N) {
    int wave = threadIdx.x >> 6;
    int lane = threadIdx.x & 63;
    int n0 = (blockIdx.x * 4 + wave) * 4;
    if (n0 >= N) return;
#pragma unroll
    for (int it = 0; it < 2; ++it) {
        int a = n0 + it * 2;
        if (a >= N) return;
        int bn = a + 1;
        bool hasB = bn < N;
        int cntA = deg[a << 4];
        int cntB = hasB ? deg[bn << 4] : 0;
        int rawA = csr_x[(a << 6) | lane];                 // coalesced
        int rawB = hasB ? csr_x[(bn << 6) | lane] : 0;
        _Float16 selfA = h16[(long long)a * IN_FEAT + lane];
        _Float16 selfB = hasB ? h16[(long long)bn * IN_FEAT + lane] : (_Float16)0.0f;
        int mA = cntA < CAP ? cntA : CAP;
        int mB = cntB < CAP ? cntB : CAP;
        int sidA = (lane < mA) ? rawA : 0;
        int sidB = (lane < mB) ? rawB : 0;
        float accA0 = 0.f, accA1 = 0.f, accB0 = 0.f, accB1 = 0.f;
        int mmax = mA > mB ? mA : mB;
        for (int j = 0; j < mmax; j += 8) {
            float va[8], vb[8];
#pragma unroll
            for (int k = 0; k < 8; ++k) {
                int sA = __shfl(sidA, j + k);
                int sB = __shfl(sidB, j + k);
                va[k] = (float)h16[(long long)sA * IN_FEAT + lane];
                vb[k] = (float)h16[(long long)sB * IN_FEAT + lane];
            }
#pragma unroll
            for (int k = 0; k < 8; ++k) {
                float xa = (j + k < mA) ? va[k] : 0.0f;
                float xb = (j + k < mB) ? vb[k] : 0.0f;
                if (k & 1) { accA1 += xa; accB1 += xb; }
                else       { accA0 += xa; accB0 += xb; }
            }
        }
        float meanA = (accA0 + accA1) / fmaxf((float)cntA, 1.0f);
        _Float16* xrA = (_Float16*)(csr_x + ((long long)a << 6));
        xrA[lane] = selfA;
        xrA[IN_FEAT + lane] = (_Float16)meanA;
        if (hasB) {
            float meanB = (accB0 + accB1) / fmaxf((float)cntB, 1.0f);
            _Float16* xrB = (_Float16*)(csr_x + ((long long)bn << 6));
            xrB[lane] = selfB;
            xrB[IN_FEAT + lane] = (_Float16)meanB;
        }
    }
}

// ---- K3: MFMA linear, LDS-staged W (R4, proven). ----
__global__ __launch_bounds__(256) void linear_kernel(const int* __restrict__ x_i,
        const float* __restrict__ W, const float* __restrict__ b,
        float* __restrict__ out, int N) {
    const _Float16* x = (const _Float16*)x_i;
    __shared__ _Float16 wlds[16 * 64 * 8];   // 16KB: [f=t*4+q][lane][j]
    int wave = threadIdx.x >> 6;
    int lane = threadIdx.x & 63;
    int quad = lane >> 4;
    int l16  = lane & 15;

    for (int i = threadIdx.x; i < 64 * 2 * IN_FEAT; i += 256) {
        int row = i >> 7, col = i & 127;
        int t = row >> 4, lr = row & 15;
        int q = col >> 5, qd = (col & 31) >> 3, j = col & 7;
        wlds[(((t * 4 + q) * 64) + (qd * 16 + lr)) * 8 + j] = (_Float16)W[i];
    }
    __syncthreads();

    int node_base = (blockIdx.x * 4 + wave) * 16;
    if (node_base >= N) return;

    half8 bf[4][4];
#pragma unroll
    for (int t = 0; t < 4; ++t)
#pragma unroll
        for (int q = 0; q < 4; ++q)
            bf[t][q] = *(const half8*)&wlds[((t * 4 + q) * 64 + lane) * 8];
    float bias[4];
#pragma unroll
    for (int t = 0; t < 4; ++t) bias[t] = b[16 * t + l16];

    int mrow = node_base + l16;
    if (mrow >= N) mrow = N - 1;

    floatx4 z = {0.0f, 0.0f, 0.0f, 0.0f};
    floatx4 acc[4] = {z, z, z, z};
#pragma unroll
    for (int q = 0; q < 4; ++q) {
        half8 af = *(const half8*)&x[(long long)mrow * (2 * IN_FEAT) + 32 * q + 8 * quad];
#pragma unroll
        for (int t = 0; t < 4; ++t)
            acc[t] = __builtin_amdgcn_mfma_f32_16x16x32_f16(af, bf[t][q], acc[t], 0, 0, 0);
    }
#pragma unroll
    for (int t = 0; t < 4; ++t)
#pragma unroll
        for (int r = 0; r < 4; ++r) {
            int n = node_base + quad * 4 + r;
            if (n < N)
                out[(long long)n * OUT_FEAT + 16 * t + l16] = acc[t][r] + bias[t];
        }
}

extern "C" void kernel_launch(void* const* d_in, const int* in_sizes, int n_in,
                              void* d_out, int out_size, void* d_ws, size_t ws_size,
                              hipStream_t stream) {
    const float* h   = (const float*)d_in[0];
    const int*   src = (const int*)d_in[1];
    const int*   dst = (const int*)d_in[2];
    const float* W   = (const float*)d_in[3];
    const float* b   = (const float*)d_in[4];
    float* out = (float*)d_out;

    int N = in_sizes[0] / IN_FEAT;   // 100000
    int E = in_sizes[1];             // 1600000

    // ws (ints): deg[N*16] (line-padded) | csr[N*64] = 32MB
    // (ws >= 38.8MB proven in R5: the fused branch ran there).
    int* deg = (int*)d_ws;
    int* csr = deg + (size_t)N * DEGS;
    // h16 lives in the front 12.8 MB of d_out (dead until linear_kernel
    // rewrites d_out; linear reads only from ws -> no race).
    _Float16* h16 = (_Float16*)out;

    int total8 = N * IN_FEAT / 8;
    int grid0 = ((total8 > (N * DEGS) / 4 ? total8 : (N * DEGS) / 4) + 255) / 256;
    conv_kernel<<<grid0, 256, 0, stream>>>(h, h16, total8, deg, N);

    int shard_sz = (N + NSHARD - 1) / NSHARD;   // 12500
    fill_kernel<<<NSHARD * BLKS_PER_SHARD, 256, 0, stream>>>(src, dst, deg, csr, E, shard_sz);

    int gather_blocks = (N + 15) / 16;       // 4 waves x 4 nodes (2 pairs)
    gather_kernel<<<gather_blocks, 256, 0, stream>>>(h16, deg, csr, N);

    int tiles = (N + 15) / 16;
    linear_kernel<<<(tiles + 3) / 4, 256, 0, stream>>>(csr, W, b, out, N);
}

// Round 8
// 171.119 us; speedup vs baseline: 1.3040x; 1.2322x over previous
//
#include <hip/hip_runtime.h>

#define IN_FEAT 64
#define OUT_FEAT 64
#define CAP 48    // csr capacity; deg~Poisson(16), P(>48)<=3e-10/node
#define NB 196    // node buckets of 512 (ceil(100000/512)); dst>>9
#define BUFCAP 64 // route LDS staging per bucket per round
#define QPAD 16   // qtail stride: one 64B line per bucket counter
#define ROUTE_BLOCKS 256

typedef __attribute__((ext_vector_type(8))) _Float16 half8;
typedef __attribute__((ext_vector_type(4))) float floatx4;
typedef __attribute__((ext_vector_type(4))) int intx4;

// ---- K0: h (f32) -> h16 (f16), 8 elems/thread; qtail-zeroing folded in ----
__global__ __launch_bounds__(256) void conv_kernel(const float* __restrict__ h,
        _Float16* __restrict__ h16, int total8, int* __restrict__ qtail) {
    int t = blockIdx.x * 256 + threadIdx.x;
    if (t < (NB * QPAD) / 4) ((intx4*)qtail)[t] = (intx4){0, 0, 0, 0};
    if (t >= total8) return;
    const float4* p = (const float4*)(h + (long long)t * 8);
    float4 a = p[0], c = p[1];
    half8 v;
    v[0] = (_Float16)a.x; v[1] = (_Float16)a.y;
    v[2] = (_Float16)a.z; v[3] = (_Float16)a.w;
    v[4] = (_Float16)c.x; v[5] = (_Float16)c.y;
    v[6] = (_Float16)c.z; v[7] = (_Float16)c.w;
    *(half8*)(h16 + (long long)t * 8) = v;
}

// ---- K1a: route edges into per-bucket queues. ----
// Fill's 3.2M scattered global ops (atomic+store per edge) were the wall
// (invariant to occupancy/MLP/CAP/deg-padding, R1-R7). Here each edge costs
// one LDS atomic + one LDS store; global traffic is per-round per-bucket:
// 1 line-padded atomic + one ~84B coalesced chunk write (~300K scattered
// ops total, 10x fewer). Single scan of the edge list (was 8x).
__global__ __launch_bounds__(512) void route_kernel(const int* __restrict__ src,
        const int* __restrict__ dst, int* __restrict__ qtail,
        int* __restrict__ queue, int E, int qcap, int epb) {
    __shared__ int cnt[NB];
    __shared__ int sbase[NB];
    __shared__ __align__(16) int buf[NB * BUFCAP];   // 50KB
    int tid = threadIdx.x;
    int eb = blockIdx.x * epb;
    int ee = eb + epb; if (ee > E) ee = E;
    for (int r0 = eb; r0 < ee; r0 += 512 * 8) {
        for (int i = tid; i < NB; i += 512) cnt[i] = 0;
        __syncthreads();
#pragma unroll
        for (int k = 0; k < 8; ++k) {
            int e = r0 + k * 512 + tid;              // coalesced per k
            if (e < ee) {
                int d = dst[e];
                int s = src[e];
                int b = d >> 9;
                int entry = ((d & 511) << 17) | s;   // src < 2^17
                int pos = atomicAdd(&cnt[b], 1);
                if (pos < BUFCAP) buf[b * BUFCAP + pos] = entry;
                else {   // statistically ~never; correct fallback
                    int p2 = atomicAdd(&qtail[b * QPAD], 1);
                    if (p2 < qcap) queue[(long long)b * qcap + p2] = entry;
                }
            }
        }
        __syncthreads();
        if (tid < NB) {   // reserve queue space: wave-parallel atomics
            int n = cnt[tid]; if (n > BUFCAP) n = BUFCAP;
            sbase[tid] = (n > 0) ? atomicAdd(&qtail[tid * QPAD], n) : 0;
        }
        __syncthreads();
        // wave-cooperative flush: lanes 0..n-1 copy bucket b in one store
        int w = tid >> 6, lane = tid & 63;
        int b1 = w * 25 + 25; if (b1 > NB) b1 = NB;
        for (int b = w * 25; b < b1; ++b) {
            int n = cnt[b]; if (n > BUFCAP) n = BUFCAP;
            if (lane < n) {
                int p = sbase[b] + lane;
                if (p < qcap) queue[(long long)b * qcap + p] = buf[b * BUFCAP + lane];
            }
        }
        __syncthreads();   // cnt reused next round
    }
}

// ---- K1b: build csr rows + deg in LDS, stream out coalesced. ----
// One block per bucket (512 nodes). All per-edge scatter hits LDS;
// global side is coalesced queue reads + coalesced row/deg writes.
__global__ __launch_bounds__(512, 1) void build_kernel(const int* __restrict__ qtail,
        const int* __restrict__ queue, int* __restrict__ deg,
        int* __restrict__ csr, int N, int qcap) {
    __shared__ __align__(16) int lcsr[512 * CAP];    // 98KB
    __shared__ int ldeg[512];
    int tid = threadIdx.x;
    int bid = blockIdx.x;
    if (tid < 512) ldeg[tid] = 0;
    __syncthreads();
    int qn = qtail[bid * QPAD]; if (qn > qcap) qn = qcap;
    long long qb = (long long)bid * qcap;
    for (int i = tid; i < qn; i += 512) {
        int e = queue[qb + i];
        int dl = e >> 17;
        int s = e & 0x1FFFF;
        int pos = atomicAdd(&ldeg[dl], 1);
        if (pos < CAP) lcsr[dl * CAP + pos] = s;
    }
    __syncthreads();
    int base_node = bid << 9;
    int nn = N - base_node; if (nn > 512) nn = 512;
    if (nn <= 0) return;
    for (int i4 = tid; i4 < nn * (CAP / 4); i4 += 512) {
        int r = i4 / (CAP / 4), c4 = i4 % (CAP / 4);
        intx4 v = *(intx4*)&lcsr[r * CAP + c4 * 4];
        *(intx4*)&csr[((long long)(base_node + r) << 6) + c4 * 4] = v;
    }
    for (int i = tid; i < nn; i += 512) deg[base_node + i] = ldeg[i];
}

// ---- K2: gather-mean, 2-node interleaved chains (R4, proven). ----
// Writes x[n] = [h16[n] | mean f16] aliased over csr row n.
__global__ __launch_bounds__(256) void gather_kernel(const _Float16* __restrict__ h16,
        const int* __restrict__ deg, int* csr_x, int N) {
    int wave = threadIdx.x >> 6;
    int lane = threadIdx.x & 63;
    int n0 = (blockIdx.x * 4 + wave) * 4;
    if (n0 >= N) return;
#pragma unroll
    for (int it = 0; it < 2; ++it) {
        int a = n0 + it * 2;
        if (a >= N) return;
        int bn = a + 1;
        bool hasB = bn < N;
        int cntA = deg[a];
        int cntB = hasB ? deg[bn] : 0;
        int rawA = csr_x[(a << 6) | lane];                 // coalesced
        int rawB = hasB ? csr_x[(bn << 6) | lane] : 0;
        _Float16 selfA = h16[(long long)a * IN_FEAT + lane];
        _Float16 selfB = hasB ? h16[(long long)bn * IN_FEAT + lane] : (_Float16)0.0f;
        int mA = cntA < CAP ? cntA : CAP;
        int mB = cntB < CAP ? cntB : CAP;
        int sidA = (lane < mA) ? rawA : 0;
        int sidB = (lane < mB) ? rawB : 0;
        float accA0 = 0.f, accA1 = 0.f, accB0 = 0.f, accB1 = 0.f;
        int mmax = mA > mB ? mA : mB;
        for (int j = 0; j < mmax; j += 8) {
            float va[8], vb[8];
#pragma unroll
            for (int k = 0; k < 8; ++k) {
                int sA = __shfl(sidA, j + k);
                int sB = __shfl(sidB, j + k);
                va[k] = (float)h16[(long long)sA * IN_FEAT + lane];
                vb[k] = (float)h16[(long long)sB * IN_FEAT + lane];
            }
#pragma unroll
            for (int k = 0; k < 8; ++k) {
                float xa = (j + k < mA) ? va[k] : 0.0f;
                float xb = (j + k < mB) ? vb[k] : 0.0f;
                if (k & 1) { accA1 += xa; accB1 += xb; }
                else       { accA0 += xa; accB0 += xb; }
            }
        }
        float meanA = (accA0 + accA1) / fmaxf((float)cntA, 1.0f);
        _Float16* xrA = (_Float16*)(csr_x + ((long long)a << 6));
        xrA[lane] = selfA;
        xrA[IN_FEAT + lane] = (_Float16)meanA;
        if (hasB) {
            float meanB = (accB0 + accB1) / fmaxf((float)cntB, 1.0f);
            _Float16* xrB = (_Float16*)(csr_x + ((long long)bn << 6));
            xrB[lane] = selfB;
            xrB[IN_FEAT + lane] = (_Float16)meanB;
        }
    }
}

// ---- K3: MFMA linear, LDS-staged W (R4, proven). ----
__global__ __launch_bounds__(256) void linear_kernel(const int* __restrict__ x_i,
        const float* __restrict__ W, const float* __restrict__ b,
        float* __restrict__ out, int N) {
    const _Float16* x = (const _Float16*)x_i;
    __shared__ _Float16 wlds[16 * 64 * 8];   // 16KB: [f=t*4+q][lane][j]
    int wave = threadIdx.x >> 6;
    int lane = threadIdx.x & 63;
    int quad = lane >> 4;
    int l16  = lane & 15;

    for (int i = threadIdx.x; i < 64 * 2 * IN_FEAT; i += 256) {
        int row = i >> 7, col = i & 127;
        int t = row >> 4, lr = row & 15;
        int q = col >> 5, qd = (col & 31) >> 3, j = col & 7;
        wlds[(((t * 4 + q) * 64) + (qd * 16 + lr)) * 8 + j] = (_Float16)W[i];
    }
    __syncthreads();

    int node_base = (blockIdx.x * 4 + wave) * 16;
    if (node_base >= N) return;

    half8 bf[4][4];
#pragma unroll
    for (int t = 0; t < 4; ++t)
#pragma unroll
        for (int q = 0; q < 4; ++q)
            bf[t][q] = *(const half8*)&wlds[((t * 4 + q) * 64 + lane) * 8];
    float bias[4];
#pragma unroll
    for (int t = 0; t < 4; ++t) bias[t] = b[16 * t + l16];

    int mrow = node_base + l16;
    if (mrow >= N) mrow = N - 1;

    floatx4 z = {0.0f, 0.0f, 0.0f, 0.0f};
    floatx4 acc[4] = {z, z, z, z};
#pragma unroll
    for (int q = 0; q < 4; ++q) {
        half8 af = *(const half8*)&x[(long long)mrow * (2 * IN_FEAT) + 32 * q + 8 * quad];
#pragma unroll
        for (int t = 0; t < 4; ++t)
            acc[t] = __builtin_amdgcn_mfma_f32_16x16x32_f16(af, bf[t][q], acc[t], 0, 0, 0);
    }
#pragma unroll
    for (int t = 0; t < 4; ++t)
#pragma unroll
        for (int r = 0; r < 4; ++r) {
            int n = node_base + quad * 4 + r;
            if (n < N)
                out[(long long)n * OUT_FEAT + 16 * t + l16] = acc[t][r] + bias[t];
        }
}

extern "C" void kernel_launch(void* const* d_in, const int* in_sizes, int n_in,
                              void* d_out, int out_size, void* d_ws, size_t ws_size,
                              hipStream_t stream) {
    const float* h   = (const float*)d_in[0];
    const int*   src = (const int*)d_in[1];
    const int*   dst = (const int*)d_in[2];
    const float* W   = (const float*)d_in[3];
    const float* b   = (const float*)d_in[4];
    float* out = (float*)d_out;

    int N = in_sizes[0] / IN_FEAT;   // 100000
    int E = in_sizes[1];             // 1600000

    // ws (ints): deg[N] | csr[N*64] | qtail[NB*16] | queue[NB*qcap] ~ 33.3MB
    // (ws >= 38.8MB proven in R5: the fused branch ran there).
    int* deg   = (int*)d_ws;
    int* csr   = deg + N;
    int* qtail = csr + (size_t)N * 64;
    int* queue = qtail + NB * QPAD;
    // h16 lives in the front 12.8 MB of d_out (dead until linear_kernel
    // rewrites d_out; linear reads only from ws -> no race).
    _Float16* h16 = (_Float16*)out;

    int qcap = (int)((long long)E * 512 / N) + 1024;   // 9216: mean+11sigma
    int epb  = (E + ROUTE_BLOCKS - 1) / ROUTE_BLOCKS;  // 6250
    int nbr  = (N + 511) >> 9;                         // 196 (<= NB)

    int total8 = N * IN_FEAT / 8;
    conv_kernel<<<(total8 + 255) / 256, 256, 0, stream>>>(h, h16, total8, qtail);

    route_kernel<<<ROUTE_BLOCKS, 512, 0, stream>>>(src, dst, qtail, queue, E, qcap, epb);
    build_kernel<<<nbr, 512, 0, stream>>>(qtail, queue, deg, csr, N, qcap);

    int gather_blocks = (N + 15) / 16;       // 4 waves x 4 nodes (2 pairs)
    gather_kernel<<<gather_blocks, 256, 0, stream>>>(h16, deg, csr, N);

    int tiles = (N + 15) / 16;
    linear_kernel<<<(tiles + 3) / 4, 256, 0, stream>>>(csr, W, b, out, N);
}